// Round 3
// baseline (845.268 us; speedup 1.0000x reference)
//
#include <hip/hip_runtime.h>
#include <hip/hip_bf16.h>

#define B_DIM 4096
#define I_DIM 1024
#define H_DIM 2048

typedef __attribute__((ext_vector_type(4))) float f32x4;
typedef __attribute__((ext_vector_type(8))) __bf16 bf16x8;

static __device__ __forceinline__ unsigned short f2bf(float f) {
  unsigned int u = __builtin_bit_cast(unsigned int, f);
  u += 0x7fffu + ((u >> 16) & 1u);   // round-to-nearest-even
  return (unsigned short)(u >> 16);
}

// Generic strided fp32 -> packed bf16 converter (float4 / ushort4 vectorized).
__global__ void cvt_f32_bf16(const float* __restrict__ src,
                             unsigned short* __restrict__ dst,
                             int total4, int cols4, int src_ld4, int col04) {
  int t = blockIdx.x * blockDim.x + threadIdx.x;
  if (t >= total4) return;
  int row = t / cols4;
  int c = t - row * cols4;
  float4 v = reinterpret_cast<const float4*>(src)[(size_t)row * src_ld4 + col04 + c];
  ushort4 o;
  o.x = f2bf(v.x); o.y = f2bf(v.y); o.z = f2bf(v.z); o.w = f2bf(v.w);
  reinterpret_cast<ushort4*>(dst)[t] = o;
}

#define GLOAD_LDS16(gp, lp)                                                     \
  __builtin_amdgcn_global_load_lds(                                             \
      (const __attribute__((address_space(1))) void*)(gp),                      \
      (__attribute__((address_space(3))) void*)(lp), 16, 0, 0)

// Fused dual GEMM: C1 = A @ B1^T, C2 = A @ B2^T  (A:[B][K] bf16, B*:[N=2048][K] bf16)
// MODE 0: precompute  -> out1 = C1 + add1[col] (input_contrib), out2 = C2 (x_tau)
// MODE 1: liquid step -> tau = tau_base*(0.5+sigmoid(add1 + C1 + tau_bias));
//                        act = tanh(C2 + add2); hn = hp + DT*(act-hp)/tau
//                        out1 = hn (f32), hbf_out = bf16(hn), out2 = tau (if WRITE_TAU)
// NOTE: hprev and out2 may ALIAS (step 5 reads h4 from and writes tau to the
// same d_out half) -> they must NOT be __restrict__, and hp is loaded before
// any store in the per-element body.
template<int K, int MODE, bool WRITE_TAU>
__global__ __launch_bounds__(256, 2)
void dual_gemm(const unsigned short* __restrict__ Ab,
               const unsigned short* __restrict__ B1b,
               const unsigned short* __restrict__ B2b,
               const float* __restrict__ add1,
               const float* __restrict__ add2,
               const float* __restrict__ tau_base,
               const float* __restrict__ tau_bias,
               const float* hprev,                 // may alias out2 (step 5)
               float* __restrict__ out1,
               float* out2,                        // may alias hprev (step 5)
               unsigned short* __restrict__ hbf_out) {
  __shared__ __align__(16) unsigned short lds[3 * 128 * 64];
  unsigned short* As  = lds;
  unsigned short* B1s = lds + 8192;
  unsigned short* B2s = lds + 16384;

  const int tid  = threadIdx.x;
  const int lane = tid & 63;
  const int wid  = tid >> 6;
  const int wm   = wid >> 1;   // 2x2 wave grid, each wave owns 64x64 output
  const int wn   = wid & 1;
  const int bm   = blockIdx.x; // over B/128
  const int bn   = blockIdx.y; // over H/128

  const unsigned short* Ap  = Ab  + (size_t)bm * 128 * K;
  const unsigned short* B1p = B1b + (size_t)bn * 128 * K;
  const unsigned short* B2p = B2b + (size_t)bn * 128 * K;

  f32x4 acc1[4][4], acc2[4][4];
  const f32x4 fz = {0.f, 0.f, 0.f, 0.f};
  #pragma unroll
  for (int i = 0; i < 4; ++i)
    #pragma unroll
    for (int j = 0; j < 4; ++j) { acc1[i][j] = fz; acc2[i][j] = fz; }

  const int lr  = lane & 15;
  const int lk8 = (lane >> 4) * 8;

  for (int ks = 0; ks < K / 64; ++ks) {
    const int k0 = ks * 64;
    // stage A, B1, B2 tiles (128x64 bf16 each) via direct global->LDS, 16B/lane
    #pragma unroll
    for (int c = 0; c < 4; ++c) {
      const int f  = c * 2048 + tid * 8;   // flat bf16 element in [128][64] tile
      const int r  = f >> 6;
      const int cc = f & 63;
      GLOAD_LDS16(Ap  + (size_t)r * K + k0 + cc, As  + f);
      GLOAD_LDS16(B1p + (size_t)r * K + k0 + cc, B1s + f);
      GLOAD_LDS16(B2p + (size_t)r * K + k0 + cc, B2s + f);
    }
    __syncthreads();
    #pragma unroll
    for (int kk = 0; kk < 2; ++kk) {
      const int kofs = kk * 32 + lk8;
      bf16x8 a[4], b1[4], b2[4];
      #pragma unroll
      for (int i = 0; i < 4; ++i)
        a[i] = *reinterpret_cast<const bf16x8*>(As + (wm * 64 + i * 16 + lr) * 64 + kofs);
      #pragma unroll
      for (int j = 0; j < 4; ++j) {
        b1[j] = *reinterpret_cast<const bf16x8*>(B1s + (wn * 64 + j * 16 + lr) * 64 + kofs);
        b2[j] = *reinterpret_cast<const bf16x8*>(B2s + (wn * 64 + j * 16 + lr) * 64 + kofs);
      }
      #pragma unroll
      for (int i = 0; i < 4; ++i)
        #pragma unroll
        for (int j = 0; j < 4; ++j) {
          acc1[i][j] = __builtin_amdgcn_mfma_f32_16x16x32_bf16(a[i], b1[j], acc1[i][j], 0, 0, 0);
          acc2[i][j] = __builtin_amdgcn_mfma_f32_16x16x32_bf16(a[i], b2[j], acc2[i][j], 0, 0, 0);
        }
    }
    __syncthreads();
  }

  // C/D layout (verified m89/m91): col = lane&15, row = (lane>>4)*4 + reg
  const int rowbase = bm * 128 + wm * 64 + (lane >> 4) * 4;
  const int colbase = bn * 128 + wn * 64 + lr;
  #pragma unroll
  for (int j = 0; j < 4; ++j) {
    const int col = colbase + j * 16;
    float tb = 0.f, tbi = 0.f, w1b = 0.f;
    if constexpr (MODE == 1) { tb = tau_base[col]; tbi = tau_bias[col]; }
    else                     { w1b = add1[col]; }
    #pragma unroll
    for (int i = 0; i < 4; ++i) {
      const f32x4 c1 = acc1[i][j];
      const f32x4 c2 = acc2[i][j];
      #pragma unroll
      for (int r = 0; r < 4; ++r) {
        const int row = rowbase + i * 16 + r;
        const size_t idx = (size_t)row * H_DIM + col;
        if constexpr (MODE == 0) {
          out1[idx] = c1[r] + w1b;
          out2[idx] = c2[r];
        } else {
          const float hp  = hprev[idx];          // MUST precede out2 store (may alias)
          const float tl  = add1[idx] + c1[r] + tbi;
          const float tau = tb * (0.5f + 1.f / (1.f + __expf(-tl)));
          const float pre = c2[r] + add2[idx];
          const float act = 1.f - 2.f / (1.f + __expf(2.f * pre)); // tanh
          const float hn  = hp + 0.1f * (act - hp) / tau;
          out1[idx] = hn;
          hbf_out[idx] = f2bf(hn);
          if constexpr (WRITE_TAU) out2[idx] = tau;
        }
      }
    }
  }
}

extern "C" void kernel_launch(void* const* d_in, const int* in_sizes, int n_in,
                              void* d_out, int out_size, void* d_ws, size_t ws_size,
                              hipStream_t stream) {
  const float* x           = (const float*)d_in[0];
  const float* hidden      = (const float*)d_in[1];
  const float* W_rec       = (const float*)d_in[2];
  const float* W_in_w      = (const float*)d_in[3];
  const float* W_in_b      = (const float*)d_in[4];
  const float* tau_base    = (const float*)d_in[5];
  const float* tau_adapt_w = (const float*)d_in[6];
  const float* tau_adapt_b = (const float*)d_in[7];

  float* out_h   = (float*)d_out;                         // final h   [4096][2048]
  float* out_tau = (float*)d_out + (size_t)B_DIM * H_DIM; // final tau [4096][2048]

  // workspace layout (128 MB total)
  char* ws = (char*)d_ws;
  if (ws_size < 134217728u) return; // insufficient scratch -> fail loudly
  unsigned short* x_bf    = (unsigned short*)(ws);              //  8.4 MB [4096][1024]
  unsigned short* hA_bf   = (unsigned short*)(ws +  8388608);   // 16.8 MB [4096][2048]
  unsigned short* hB_bf   = (unsigned short*)(ws + 25165824);   // 16.8 MB
  unsigned short* Win_bf  = (unsigned short*)(ws + 41943040);   //  4.2 MB [2048][1024]
  unsigned short* Wxt_bf  = (unsigned short*)(ws + 46137344);   //  4.2 MB [2048][1024]
  unsigned short* Wrec_bf = (unsigned short*)(ws + 50331648);   //  8.4 MB [2048][2048]
  unsigned short* Wh_bf   = (unsigned short*)(ws + 58720256);   //  8.4 MB [2048][2048]
  float*          ic      = (float*)(ws + 67108864);            // 33.5 MB input_contrib
  float*          xtau    = (float*)(ws + 100663296);           // 33.5 MB x_tau

  // ---- bf16 conversions (src, dst, total4, cols4, src_ld4, col04) ----
  cvt_f32_bf16<<<(1048576 + 255) / 256, 256, 0, stream>>>(x,           x_bf,    1048576, 256, 256,   0);
  cvt_f32_bf16<<<(2097152 + 255) / 256, 256, 0, stream>>>(hidden,      hA_bf,   2097152, 512, 512,   0);
  cvt_f32_bf16<<<( 524288 + 255) / 256, 256, 0, stream>>>(W_in_w,      Win_bf,   524288, 256, 256,   0);
  cvt_f32_bf16<<<( 524288 + 255) / 256, 256, 0, stream>>>(tau_adapt_w, Wxt_bf,   524288, 256, 768,   0);
  cvt_f32_bf16<<<(1048576 + 255) / 256, 256, 0, stream>>>(tau_adapt_w, Wh_bf,   1048576, 512, 768, 256);
  cvt_f32_bf16<<<(1048576 + 255) / 256, 256, 0, stream>>>(W_rec,       Wrec_bf, 1048576, 512, 512,   0);

  dim3 grid(B_DIM / 128, H_DIM / 128); // (32, 16)

  // ---- loop-invariant: input_contrib = x@W_in^T + b ; x_tau = x@Wxt^T ----
  dual_gemm<1024, 0, false><<<grid, 256, 0, stream>>>(
      x_bf, Win_bf, Wxt_bf, W_in_b, nullptr, nullptr, nullptr, nullptr,
      ic, xtau, nullptr);

  // ---- 5 liquid steps; h f32 ping-pongs through d_out halves ----
  dual_gemm<2048, 1, false><<<grid, 256, 0, stream>>>(
      hA_bf, Wh_bf, Wrec_bf, xtau, ic, tau_base, tau_adapt_b, hidden,
      out_h, nullptr, hB_bf);                                   // h1
  dual_gemm<2048, 1, false><<<grid, 256, 0, stream>>>(
      hB_bf, Wh_bf, Wrec_bf, xtau, ic, tau_base, tau_adapt_b, out_h,
      out_tau, nullptr, hA_bf);                                 // h2
  dual_gemm<2048, 1, false><<<grid, 256, 0, stream>>>(
      hA_bf, Wh_bf, Wrec_bf, xtau, ic, tau_base, tau_adapt_b, out_tau,
      out_h, nullptr, hB_bf);                                   // h3
  dual_gemm<2048, 1, false><<<grid, 256, 0, stream>>>(
      hB_bf, Wh_bf, Wrec_bf, xtau, ic, tau_base, tau_adapt_b, out_h,
      out_tau, nullptr, hA_bf);                                 // h4
  dual_gemm<2048, 1, true><<<grid, 256, 0, stream>>>(
      hA_bf, Wh_bf, Wrec_bf, xtau, ic, tau_base, tau_adapt_b, out_tau,
      out_h, out_tau, hB_bf);                                   // h5 + tau
}

// Round 4
// 786.825 us; speedup vs baseline: 1.0743x; 1.0743x over previous
//
#include <hip/hip_runtime.h>
#include <hip/hip_bf16.h>

#define B_DIM 4096
#define I_DIM 1024
#define H_DIM 2048

typedef __attribute__((ext_vector_type(4))) float f32x4;
typedef __attribute__((ext_vector_type(8))) __bf16 bf16x8;

static __device__ __forceinline__ unsigned short f2bf(float f) {
  unsigned int u = __builtin_bit_cast(unsigned int, f);
  u += 0x7fffu + ((u >> 16) & 1u);   // round-to-nearest-even
  return (unsigned short)(u >> 16);
}
static __device__ __forceinline__ float bf2f(unsigned short u) {
  unsigned int v = (unsigned int)u << 16;
  return __builtin_bit_cast(float, v);
}

// Generic strided fp32 -> packed bf16 converter (float4 / ushort4 vectorized).
__global__ void cvt_f32_bf16(const float* __restrict__ src,
                             unsigned short* __restrict__ dst,
                             int total4, int cols4, int src_ld4, int col04) {
  int t = blockIdx.x * blockDim.x + threadIdx.x;
  if (t >= total4) return;
  int row = t / cols4;
  int c = t - row * cols4;
  float4 v = reinterpret_cast<const float4*>(src)[(size_t)row * src_ld4 + col04 + c];
  ushort4 o;
  o.x = f2bf(v.x); o.y = f2bf(v.y); o.z = f2bf(v.z); o.w = f2bf(v.w);
  reinterpret_cast<ushort4*>(dst)[t] = o;
}

// Interleaving converter: source row sr -> dst row ((sr>>4)<<5) + (sr&15) + which*16.
// Builds the 16-row-group interleaved concat weight (even groups = which 0,
// odd groups = which 1) so one GEMM computes both matmuls with paired columns.
__global__ void cvt_ilv_bf16(const float* __restrict__ src,
                             unsigned short* __restrict__ dst,
                             int total4, int cols4, int src_ld4, int col04, int which) {
  int t = blockIdx.x * blockDim.x + threadIdx.x;
  if (t >= total4) return;
  int srow = t / cols4;
  int c = t - srow * cols4;
  int drow = ((srow >> 4) << 5) + (srow & 15) + which * 16;
  float4 v = reinterpret_cast<const float4*>(src)[(size_t)srow * src_ld4 + col04 + c];
  ushort4 o;
  o.x = f2bf(v.x); o.y = f2bf(v.y); o.z = f2bf(v.z); o.w = f2bf(v.w);
  reinterpret_cast<ushort4*>(dst)[(size_t)drow * cols4 + c] = o;
}

#define GLOAD_LDS16(gp, lp)                                                     \
  __builtin_amdgcn_global_load_lds(                                             \
      (const __attribute__((address_space(1))) void*)(gp),                      \
      (__attribute__((address_space(3))) void*)(lp), 16, 0, 0)

// Swizzled LDS fragment read: tile is [256 rows][32 bf16], 16B slots permuted
// within each row by k16 ^= (row>>1)&3 (matching the inverse-swizzled staging
// source). Gives 2-way (free) bank aliasing on the 16-lanes-16-rows frag read.
static __device__ __forceinline__ bf16x8 ldfrag(const unsigned short* p, int row, int l16) {
  return *reinterpret_cast<const bf16x8*>(p + row * 32 + ((l16 ^ ((row >> 1) & 3)) << 3));
}

// 256x256-tile GEMM, 8 waves (2M x 4N), BK=32, triple-buffered LDS,
// counted-vmcnt pipeline (T3/T4), setprio around MFMA (T5), swizzled LDS (T2).
// A: [4096][K] bf16.  W: [4096][K] bf16 interleaved (even 16-group = role-1,
// odd = role-2).  Output C[m][2048] pairs: acc[i][even j] = role-1 value,
// acc[i][odd j] = role-2 value for the SAME output column.
// MODE 0 (precompute): ob1 = bf16(C1 + wb[col]) (input_contrib), ob2 = bf16(C2) (x_tau)
// MODE 1 (step): tau = tau_base*(0.5+sigmoid(xtau + C1 + tau_bias));
//                act = tanh(C2 + ic); hn = hp + 0.1*(act-hp)/tau
//                out1 = hn f32, ob1 = bf16(hn), out2 = tau f32 (if WRITE_TAU)
// hprev/out2 may alias (step 5) -> no __restrict__, hp loaded before stores.
template<int K, int MODE, bool WRITE_TAU>
__global__ __launch_bounds__(512, 2)
void gemm256(const unsigned short* __restrict__ Ab,
             const unsigned short* __restrict__ Wb,
             const unsigned short* __restrict__ add1b,   // MODE1: xtau bf16
             const unsigned short* __restrict__ add2b,   // MODE1: ic bf16
             const float* __restrict__ wb,               // MODE0: W_in_b
             const float* __restrict__ tau_base,
             const float* __restrict__ tau_bias,
             const float* hprev,                         // may alias out2
             float* __restrict__ out1,
             float* out2,                                // may alias hprev
             unsigned short* __restrict__ ob1,
             unsigned short* __restrict__ ob2) {
  __shared__ __align__(16) unsigned short lds[49152];   // 3 x (A 16KB + B 16KB)

  const int tid  = threadIdx.x;
  const int lane = tid & 63;
  const int wid  = tid >> 6;      // 0..7
  const int wm   = wid >> 2;      // 0..1  (M half)
  const int wn   = wid & 3;       // 0..3  (N quarter)
  const int lr   = lane & 15;
  const int l16  = lane >> 4;

  // XCD-aware swizzle: 256 blocks, 8 XCDs -> 32 consecutive per XCD
  const int bid = blockIdx.x;
  const int swz = (bid & 7) * 32 + (bid >> 3);
  const int bm = swz >> 4;        // 0..15
  const int bn = swz & 15;        // 0..15

  const unsigned short* Ag = Ab + (size_t)bm * 256 * K;
  const unsigned short* Wg = Wb + (size_t)bn * 256 * K;

  constexpr int NT = K / 32;

  // stage one 256x32 operand tile (2 x global_load_lds / thread, 16B each);
  // linear LDS dest slot s, source k16 inverse-swizzled so LDS holds the
  // swizzled layout that ldfrag() reads.
#define STAGE_OP(gcol, ldsbase)                                              \
  {                                                                          \
    { int s = tid;                                                           \
      int row = s >> 2;                                                      \
      int k16 = (s & 3) ^ ((row >> 1) & 3);                                  \
      GLOAD_LDS16((gcol) + (size_t)row * K + (k16 << 3),                     \
                  lds + (ldsbase) + s * 8); }                                \
    { int s = 512 + tid;                                                     \
      int row = s >> 2;                                                      \
      int k16 = (s & 3) ^ ((row >> 1) & 3);                                  \
      GLOAD_LDS16((gcol) + (size_t)row * K + (k16 << 3),                     \
                  lds + (ldsbase) + s * 8); }                                \
  }

  // prologue: stage K-tiles 0 and 1; wait for tile 0 (vmcnt(4): tile 1 stays
  // in flight), barrier so ALL waves' tile-0 loads have landed.
  STAGE_OP(Ag, 0);
  STAGE_OP(Wg, 8192);
  STAGE_OP(Ag + 32, 16384);
  STAGE_OP(Wg + 32, 16384 + 8192);
  asm volatile("s_waitcnt vmcnt(4)" ::: "memory");
  __builtin_amdgcn_s_barrier();

  f32x4 acc[8][4];
  const f32x4 fz = {0.f, 0.f, 0.f, 0.f};
  #pragma unroll
  for (int i = 0; i < 8; ++i)
    #pragma unroll
    for (int j = 0; j < 4; ++j) acc[i][j] = fz;

  bf16x8 afr[4], bfr[4];
  int cb = 0;                                    // (t%3)*16384
  for (int t = 0; t < NT; ++t) {
    int nb = cb + 32768; if (nb >= 49152) nb -= 49152;   // buffer for t+2
    const unsigned short* Acur = lds + cb;
    const unsigned short* Bcur = lds + cb + 8192;

    // ---- phase A: quadrant i=0..3 x j=0..3; stage A-tile of t+2 ----
    #pragma unroll
    for (int i = 0; i < 4; ++i) afr[i] = ldfrag(Acur, wm * 128 + i * 16 + lr, l16);
    #pragma unroll
    for (int j = 0; j < 4; ++j) bfr[j] = ldfrag(Bcur, wn * 64 + j * 16 + lr, l16);
    if (t + 2 < NT) { STAGE_OP(Ag + (size_t)(t + 2) * 32, nb); }
    asm volatile("" ::: "memory");
    __builtin_amdgcn_s_barrier();
    __builtin_amdgcn_s_setprio(1);
    #pragma unroll
    for (int i = 0; i < 4; ++i)
      #pragma unroll
      for (int j = 0; j < 4; ++j)
        acc[i][j] = __builtin_amdgcn_mfma_f32_16x16x32_bf16(afr[i], bfr[j], acc[i][j], 0, 0, 0);
    __builtin_amdgcn_s_setprio(0);
    __builtin_amdgcn_s_barrier();

    // ---- phase B: quadrant i=4..7 (B frags reused); stage B-tile of t+2 ----
    #pragma unroll
    for (int i = 0; i < 4; ++i) afr[i] = ldfrag(Acur, wm * 128 + (i + 4) * 16 + lr, l16);
    if (t + 2 < NT) { STAGE_OP(Wg + (size_t)(t + 2) * 32, nb + 8192); }
    asm volatile("" ::: "memory");
    // counted vmcnt: this group issued 4 loads (t+2); the older 4 (t+1) must
    // land before the next group reads them. Never 0 in steady state (T4).
    if (t + 2 < NT)      { asm volatile("s_waitcnt vmcnt(4)" ::: "memory"); }
    else if (t + 1 < NT) { asm volatile("s_waitcnt vmcnt(0)" ::: "memory"); }
    __builtin_amdgcn_s_barrier();
    __builtin_amdgcn_s_setprio(1);
    #pragma unroll
    for (int i = 0; i < 4; ++i)
      #pragma unroll
      for (int j = 0; j < 4; ++j)
        acc[i + 4][j] = __builtin_amdgcn_mfma_f32_16x16x32_bf16(afr[i], bfr[j], acc[i + 4][j], 0, 0, 0);
    __builtin_amdgcn_s_setprio(0);
    __builtin_amdgcn_s_barrier();

    cb += 16384; if (cb >= 49152) cb = 0;
  }
#undef STAGE_OP

  // ---- fused epilogue ----
  // C/D layout: col = lane&15, row = (lane>>4)*4 + reg (m89/m91).
  // Interleave: j even = role-1 (tau-logit / ic), j odd = role-2 (act / xtau),
  // pair (2p, 2p+1) shares output column hc.
  const int rowg0 = bm * 256 + wm * 128 + l16 * 4;
  const int hcb = bn * 128 + wn * 32;
  #pragma unroll
  for (int p = 0; p < 2; ++p) {
    const int hc = hcb + p * 16 + lr;
    float tb = 0.f, tbi = 0.f, wbv = 0.f;
    if constexpr (MODE == 1) { tb = tau_base[hc]; tbi = tau_bias[hc]; }
    else                     { wbv = wb[hc]; }
    #pragma unroll
    for (int i = 0; i < 8; ++i) {
      const f32x4 c1 = acc[i][2 * p];
      const f32x4 c2 = acc[i][2 * p + 1];
      #pragma unroll
      for (int r = 0; r < 4; ++r) {
        const int row = rowg0 + i * 16 + r;
        const size_t idx = (size_t)row * H_DIM + hc;
        if constexpr (MODE == 0) {
          ob1[idx] = f2bf(c1[r] + wbv);
          ob2[idx] = f2bf(c2[r]);
        } else {
          const float hp  = hprev[idx];          // before stores (may alias out2)
          const float tl  = bf2f(add1b[idx]) + c1[r] + tbi;
          const float tau = tb * (0.5f + 1.f / (1.f + __expf(-tl)));
          const float pre = c2[r] + bf2f(add2b[idx]);
          const float act = 1.f - 2.f / (1.f + __expf(2.f * pre)); // tanh
          const float hn  = hp + 0.1f * (act - hp) / tau;
          out1[idx] = hn;
          ob1[idx] = f2bf(hn);
          if constexpr (WRITE_TAU) out2[idx] = tau;
        }
      }
    }
  }
}

extern "C" void kernel_launch(void* const* d_in, const int* in_sizes, int n_in,
                              void* d_out, int out_size, void* d_ws, size_t ws_size,
                              hipStream_t stream) {
  const float* x           = (const float*)d_in[0];
  const float* hidden      = (const float*)d_in[1];
  const float* W_rec       = (const float*)d_in[2];
  const float* W_in_w      = (const float*)d_in[3];
  const float* W_in_b      = (const float*)d_in[4];
  const float* tau_base    = (const float*)d_in[5];
  const float* tau_adapt_w = (const float*)d_in[6];
  const float* tau_adapt_b = (const float*)d_in[7];

  float* out_h   = (float*)d_out;
  float* out_tau = (float*)d_out + (size_t)B_DIM * H_DIM;

  char* ws = (char*)d_ws;
  if (ws_size < 100663296u) return;
  unsigned short* x_bf   = (unsigned short*)(ws);             //  8.4 MB [4096][1024]
  unsigned short* hA_bf  = (unsigned short*)(ws +  8388608);  // 16.8 MB [4096][2048]
  unsigned short* hB_bf  = (unsigned short*)(ws + 25165824);  // 16.8 MB
  unsigned short* Wpre   = (unsigned short*)(ws + 41943040);  //  8.4 MB [4096][1024] ilv
  unsigned short* Wcat   = (unsigned short*)(ws + 50331648);  // 16.8 MB [4096][2048] ilv
  unsigned short* icb    = (unsigned short*)(ws + 67108864);  // 16.8 MB bf16 input_contrib
  unsigned short* xtaub  = (unsigned short*)(ws + 83886080);  // 16.8 MB bf16 x_tau

  // ---- conversions ----
  cvt_f32_bf16<<<4096, 256, 0, stream>>>(x,      x_bf,  1048576, 256, 256, 0);
  cvt_f32_bf16<<<8192, 256, 0, stream>>>(hidden, hA_bf, 2097152, 512, 512, 0);
  // Wpre: even = W_in_w (-> ic), odd = tau_adapt_w[:, :1024] (-> x_tau)
  cvt_ilv_bf16<<<2048, 256, 0, stream>>>(W_in_w,      Wpre, 524288, 256, 256, 0, 0);
  cvt_ilv_bf16<<<2048, 256, 0, stream>>>(tau_adapt_w, Wpre, 524288, 256, 768, 0, 1);
  // Wcat: even = tau_adapt_w[:, 1024:] (-> tau logits), odd = W_rec (-> act)
  cvt_ilv_bf16<<<4096, 256, 0, stream>>>(tau_adapt_w, Wcat, 1048576, 512, 768, 256, 0);
  cvt_ilv_bf16<<<4096, 256, 0, stream>>>(W_rec,       Wcat, 1048576, 512, 512, 0,   1);

  // ---- precompute: icb = bf16(x@W_in^T + b), xtaub = bf16(x@Wxt^T) ----
  gemm256<1024, 0, false><<<256, 512, 0, stream>>>(
      x_bf, Wpre, nullptr, nullptr, W_in_b, nullptr, nullptr, nullptr,
      nullptr, nullptr, icb, xtaub);

  // ---- 5 liquid steps; h f32 ping-pongs through d_out halves ----
  gemm256<2048, 1, false><<<256, 512, 0, stream>>>(
      hA_bf, Wcat, xtaub, icb, nullptr, tau_base, tau_adapt_b, hidden,
      out_h, nullptr, hB_bf, nullptr);                          // h1
  gemm256<2048, 1, false><<<256, 512, 0, stream>>>(
      hB_bf, Wcat, xtaub, icb, nullptr, tau_base, tau_adapt_b, out_h,
      out_tau, nullptr, hA_bf, nullptr);                        // h2
  gemm256<2048, 1, false><<<256, 512, 0, stream>>>(
      hA_bf, Wcat, xtaub, icb, nullptr, tau_base, tau_adapt_b, out_tau,
      out_h, nullptr, hB_bf, nullptr);                          // h3
  gemm256<2048, 1, false><<<256, 512, 0, stream>>>(
      hB_bf, Wcat, xtaub, icb, nullptr, tau_base, tau_adapt_b, out_h,
      out_tau, nullptr, hA_bf, nullptr);                        // h4
  gemm256<2048, 1, true><<<256, 512, 0, stream>>>(
      hA_bf, Wcat, xtaub, icb, nullptr, tau_base, tau_adapt_b, out_tau,
      out_h, out_tau, hB_bf, nullptr);                          // h5 + tau
}

// Round 5
// 651.138 us; speedup vs baseline: 1.2981x; 1.2084x over previous
//
#include <hip/hip_runtime.h>
#include <hip/hip_bf16.h>

#define B_DIM 4096
#define I_DIM 1024
#define H_DIM 2048

typedef __attribute__((ext_vector_type(4))) float f32x4;
typedef __attribute__((ext_vector_type(8))) __bf16 bf16x8;

static __device__ __forceinline__ unsigned short f2bf(float f) {
  unsigned int u = __builtin_bit_cast(unsigned int, f);
  u += 0x7fffu + ((u >> 16) & 1u);   // round-to-nearest-even
  return (unsigned short)(u >> 16);
}
static __device__ __forceinline__ float bf2f(unsigned short u) {
  unsigned int v = (unsigned int)u << 16;
  return __builtin_bit_cast(float, v);
}

// Generic strided fp32 -> packed bf16 converter (float4 / ushort4 vectorized).
__global__ void cvt_f32_bf16(const float* __restrict__ src,
                             unsigned short* __restrict__ dst,
                             int total4, int cols4, int src_ld4, int col04) {
  int t = blockIdx.x * blockDim.x + threadIdx.x;
  if (t >= total4) return;
  int row = t / cols4;
  int c = t - row * cols4;
  float4 v = reinterpret_cast<const float4*>(src)[(size_t)row * src_ld4 + col04 + c];
  ushort4 o;
  o.x = f2bf(v.x); o.y = f2bf(v.y); o.z = f2bf(v.z); o.w = f2bf(v.w);
  reinterpret_cast<ushort4*>(dst)[t] = o;
}

// Interleaving converter: source row sr -> dst row ((sr>>4)<<5) + (sr&15) + which*16.
// Builds the 16-row-group interleaved concat weight (even groups = which 0,
// odd groups = which 1) so one GEMM computes both matmuls with paired columns.
__global__ void cvt_ilv_bf16(const float* __restrict__ src,
                             unsigned short* __restrict__ dst,
                             int total4, int cols4, int src_ld4, int col04, int which) {
  int t = blockIdx.x * blockDim.x + threadIdx.x;
  if (t >= total4) return;
  int srow = t / cols4;
  int c = t - srow * cols4;
  int drow = ((srow >> 4) << 5) + (srow & 15) + which * 16;
  float4 v = reinterpret_cast<const float4*>(src)[(size_t)srow * src_ld4 + col04 + c];
  ushort4 o;
  o.x = f2bf(v.x); o.y = f2bf(v.y); o.z = f2bf(v.z); o.w = f2bf(v.w);
  reinterpret_cast<ushort4*>(dst)[(size_t)drow * cols4 + c] = o;
}

#define GLOAD_LDS16(gp, lp)                                                     \
  __builtin_amdgcn_global_load_lds(                                             \
      (const __attribute__((address_space(1))) void*)(gp),                      \
      (__attribute__((address_space(3))) void*)(lp), 16, 0, 0)

// Swizzled LDS fragment read: tile rows are 32 bf16 (64 B); 16B slots permuted
// within each row by k16 ^= (row>>1)&3, matching the inverse-swizzled staging
// source. Measured 0 bank conflicts in round 4 (2-way aliasing = free).
static __device__ __forceinline__ bf16x8 ldfrag(const unsigned short* p, int row, int l16) {
  return *reinterpret_cast<const bf16x8*>(p + row * 32 + ((l16 ^ ((row >> 1) & 3)) << 3));
}

// 128(M)x256(N)-tile GEMM, 8 waves (2M x 4N, 64x64 output each), BK=32,
// TRIPLE-buffered LDS (72 KB -> 2 blocks/CU), ONE barrier per K-tile
// (race-free: loads for tile t+2 overwrite buf[(t-1)%3], whose readers all
// finished before the previous barrier), counted vmcnt(3) steady state (T4),
// setprio around MFMA (T5), both-sides LDS swizzle (T2), XCD swizzle (T1).
// A: [4096][K] bf16.  W: [4096][K] bf16 interleaved (even 16-group = role-1,
// odd = role-2); acc[i][even j] = role-1, acc[i][odd j] = role-2, pair shares
// the same H output column.
// MODE 0 (precompute): ob1 = bf16(C1 + wb[col]), ob2 = bf16(C2)
// MODE 1 (step): tau = tau_base*(0.5+sigmoid(xtau + C1 + tau_bias));
//                act = tanh(C2 + ic); hn = hp + 0.1*(act-hp)/tau
//                out1 = hn f32, ob1 = bf16(hn), out2 = tau f32 (if WRITE_TAU)
// hprev/out2 may alias (step 5) -> no __restrict__, hp loaded before stores.
template<int K, int MODE, bool WRITE_TAU>
__global__ __launch_bounds__(512, 4)
void gemm128x256(const unsigned short* __restrict__ Ab,
                 const unsigned short* __restrict__ Wb,
                 const unsigned short* __restrict__ add1b,   // MODE1: xtau bf16
                 const unsigned short* __restrict__ add2b,   // MODE1: ic bf16
                 const float* __restrict__ wb,               // MODE0: W_in_b
                 const float* __restrict__ tau_base,
                 const float* __restrict__ tau_bias,
                 const float* hprev,                         // may alias out2
                 float* __restrict__ out1,
                 float* out2,                                // may alias hprev
                 unsigned short* __restrict__ ob1,
                 unsigned short* __restrict__ ob2) {
  // 3 buffers x (A 128x32 = 4096 shorts, B 256x32 = 8192 shorts) = 72 KB
  __shared__ __align__(16) unsigned short lds[36864];

  const int tid  = threadIdx.x;
  const int lane = tid & 63;
  const int wid  = tid >> 6;      // 0..7
  const int wm   = wid >> 2;      // 0..1  (M half, 64 rows)
  const int wn   = wid & 3;       // 0..3  (N quarter, 64 cols)
  const int lr   = lane & 15;
  const int l16  = lane >> 4;

  // XCD swizzle: 512 blocks, 8 XCDs -> 64 consecutive per XCD. Within an XCD
  // the 64 concurrent blocks share a bn PAIR (2 x 1MB W panels resident in
  // its 4MB L2) and stream all 32 A panels (L3-served).
  const int bid = blockIdx.x;
  const int swz = (bid & 7) * 64 + (bid >> 3);
  const int bn = swz >> 5;        // 0..15 (256-col N tile)
  const int bm = swz & 31;        // 0..31 (128-row M tile)

  const unsigned short* Ag = Ab + (size_t)bm * 128 * K;
  const unsigned short* Wg = Wb + (size_t)bn * 256 * K;

  constexpr int NT = K / 32;

  // A-tile: 8KB = 1 gload/thread; B-tile: 16KB = 2 gloads/thread.
  // Linear LDS dest slot s; global source k16 inverse-swizzled so LDS holds
  // the swizzled layout ldfrag() reads.
#define STAGE_A(gcol, base)                                                  \
  { int s = tid; int row = s >> 2; int k16 = (s & 3) ^ ((row >> 1) & 3);     \
    GLOAD_LDS16((gcol) + (size_t)row * K + (k16 << 3),                       \
                lds + (base) + s * 8); }
#define STAGE_B(gcol, base)                                                  \
  { { int s = tid; int row = s >> 2; int k16 = (s & 3) ^ ((row >> 1) & 3);   \
      GLOAD_LDS16((gcol) + (size_t)row * K + (k16 << 3),                     \
                  lds + (base) + 4096 + s * 8); }                            \
    { int s = 512 + tid; int row = s >> 2;                                   \
      int k16 = (s & 3) ^ ((row >> 1) & 3);                                  \
      GLOAD_LDS16((gcol) + (size_t)row * K + (k16 << 3),                     \
                  lds + (base) + 4096 + s * 8); } }

  // prologue: stage tiles 0 and 1; wait tile 0 (3 loads of tile 1 in flight)
  STAGE_A(Ag, 0);
  STAGE_B(Wg, 0);
  STAGE_A(Ag + 32, 12288);
  STAGE_B(Wg + 32, 12288);
  asm volatile("s_waitcnt vmcnt(3)" ::: "memory");
  __builtin_amdgcn_s_barrier();

  f32x4 acc[4][4];
  const f32x4 fz = {0.f, 0.f, 0.f, 0.f};
  #pragma unroll
  for (int i = 0; i < 4; ++i)
    #pragma unroll
    for (int j = 0; j < 4; ++j) acc[i][j] = fz;

  int cb = 0;                                    // (t%3)*12288
  for (int t = 0; t < NT; ++t) {
    int nb = cb + 24576; if (nb >= 36864) nb -= 36864;   // buffer for t+2
    const unsigned short* Acur = lds + cb;
    const unsigned short* Bcur = lds + cb + 4096;

    bf16x8 afr[4], bfr[4];
    #pragma unroll
    for (int i = 0; i < 4; ++i) afr[i] = ldfrag(Acur, wm * 64 + i * 16 + lr, l16);
    #pragma unroll
    for (int j = 0; j < 4; ++j) bfr[j] = ldfrag(Bcur, wn * 64 + j * 16 + lr, l16);

    if (t + 2 < NT) {
      STAGE_A(Ag + (size_t)(t + 2) * 32, nb);
      STAGE_B(Wg + (size_t)(t + 2) * 32, nb);
      // counted: 6 outstanding (t+1's 3 + t+2's 3) -> wait t+1 landed
      asm volatile("s_waitcnt vmcnt(3)" ::: "memory");
    } else if (t + 1 < NT) {
      asm volatile("s_waitcnt vmcnt(0)" ::: "memory");
    }

    __builtin_amdgcn_s_setprio(1);
    #pragma unroll
    for (int i = 0; i < 4; ++i)
      #pragma unroll
      for (int j = 0; j < 4; ++j)
        acc[i][j] = __builtin_amdgcn_mfma_f32_16x16x32_bf16(afr[i], bfr[j], acc[i][j], 0, 0, 0);
    __builtin_amdgcn_s_setprio(0);
    // single barrier per tile: vmcnt(3) above ran in EVERY wave before this,
    // so buf[t+1] is fully resident for all waves' next-iteration ds_reads.
    __builtin_amdgcn_s_barrier();

    cb += 12288; if (cb >= 36864) cb = 0;
  }
#undef STAGE_A
#undef STAGE_B

  // ---- fused epilogue ----
  // C/D layout: col = lane&15, row = (lane>>4)*4 + reg (m89/m91).
  // j even = role-1 (tau-logit / ic), j odd = role-2 (act / xtau);
  // pair (2p,2p+1) shares output column hc.
  const int rowg0 = bm * 128 + wm * 64 + l16 * 4;
  const int hcb = bn * 128 + wn * 32;
  #pragma unroll
  for (int p = 0; p < 2; ++p) {
    const int hc = hcb + p * 16 + lr;
    float tb = 0.f, tbi = 0.f, wbv = 0.f;
    if constexpr (MODE == 1) { tb = tau_base[hc]; tbi = tau_bias[hc]; }
    else                     { wbv = wb[hc]; }
    #pragma unroll
    for (int i = 0; i < 4; ++i) {
      const f32x4 c1 = acc[i][2 * p];
      const f32x4 c2 = acc[i][2 * p + 1];
      #pragma unroll
      for (int r = 0; r < 4; ++r) {
        const int row = rowg0 + i * 16 + r;
        const size_t idx = (size_t)row * H_DIM + hc;
        if constexpr (MODE == 0) {
          ob1[idx] = f2bf(c1[r] + wbv);
          ob2[idx] = f2bf(c2[r]);
        } else {
          const float hp  = hprev[idx];          // before stores (may alias out2)
          const float tl  = bf2f(add1b[idx]) + c1[r] + tbi;
          const float tau = tb * (0.5f + 1.f / (1.f + __expf(-tl)));
          const float pre = c2[r] + bf2f(add2b[idx]);
          const float act = 1.f - 2.f / (1.f + __expf(2.f * pre)); // tanh
          const float hn  = hp + 0.1f * (act - hp) / tau;
          out1[idx] = hn;
          ob1[idx] = f2bf(hn);
          if constexpr (WRITE_TAU) out2[idx] = tau;
        }
      }
    }
  }
}

extern "C" void kernel_launch(void* const* d_in, const int* in_sizes, int n_in,
                              void* d_out, int out_size, void* d_ws, size_t ws_size,
                              hipStream_t stream) {
  const float* x           = (const float*)d_in[0];
  const float* hidden      = (const float*)d_in[1];
  const float* W_rec       = (const float*)d_in[2];
  const float* W_in_w      = (const float*)d_in[3];
  const float* W_in_b      = (const float*)d_in[4];
  const float* tau_base    = (const float*)d_in[5];
  const float* tau_adapt_w = (const float*)d_in[6];
  const float* tau_adapt_b = (const float*)d_in[7];

  float* out_h   = (float*)d_out;
  float* out_tau = (float*)d_out + (size_t)B_DIM * H_DIM;

  char* ws = (char*)d_ws;
  if (ws_size < 100663296u) return;
  unsigned short* x_bf   = (unsigned short*)(ws);             //  8.4 MB [4096][1024]
  unsigned short* hA_bf  = (unsigned short*)(ws +  8388608);  // 16.8 MB [4096][2048]
  unsigned short* hB_bf  = (unsigned short*)(ws + 25165824);  // 16.8 MB
  unsigned short* Wpre   = (unsigned short*)(ws + 41943040);  //  8.4 MB [4096][1024] ilv
  unsigned short* Wcat   = (unsigned short*)(ws + 50331648);  // 16.8 MB [4096][2048] ilv
  unsigned short* icb    = (unsigned short*)(ws + 67108864);  // 16.8 MB bf16 input_contrib
  unsigned short* xtaub  = (unsigned short*)(ws + 83886080);  // 16.8 MB bf16 x_tau

  // ---- conversions ----
  cvt_f32_bf16<<<4096, 256, 0, stream>>>(x,      x_bf,  1048576, 256, 256, 0);
  cvt_f32_bf16<<<8192, 256, 0, stream>>>(hidden, hA_bf, 2097152, 512, 512, 0);
  // Wpre: even = W_in_w (-> ic), odd = tau_adapt_w[:, :1024] (-> x_tau)
  cvt_ilv_bf16<<<2048, 256, 0, stream>>>(W_in_w,      Wpre, 524288, 256, 256, 0, 0);
  cvt_ilv_bf16<<<2048, 256, 0, stream>>>(tau_adapt_w, Wpre, 524288, 256, 768, 0, 1);
  // Wcat: even = tau_adapt_w[:, 1024:] (-> tau logits), odd = W_rec (-> act)
  cvt_ilv_bf16<<<4096, 256, 0, stream>>>(tau_adapt_w, Wcat, 1048576, 512, 768, 256, 0);
  cvt_ilv_bf16<<<4096, 256, 0, stream>>>(W_rec,       Wcat, 1048576, 512, 512, 0,   1);

  // ---- precompute: icb = bf16(x@W_in^T + b), xtaub = bf16(x@Wxt^T) ----
  gemm128x256<1024, 0, false><<<512, 512, 0, stream>>>(
      x_bf, Wpre, nullptr, nullptr, W_in_b, nullptr, nullptr, nullptr,
      nullptr, nullptr, icb, xtaub);

  // ---- 5 liquid steps; h f32 ping-pongs through d_out halves ----
  gemm128x256<2048, 1, false><<<512, 512, 0, stream>>>(
      hA_bf, Wcat, xtaub, icb, nullptr, tau_base, tau_adapt_b, hidden,
      out_h, nullptr, hB_bf, nullptr);                          // h1
  gemm128x256<2048, 1, false><<<512, 512, 0, stream>>>(
      hB_bf, Wcat, xtaub, icb, nullptr, tau_base, tau_adapt_b, out_h,
      out_tau, nullptr, hA_bf, nullptr);                        // h2
  gemm128x256<2048, 1, false><<<512, 512, 0, stream>>>(
      hA_bf, Wcat, xtaub, icb, nullptr, tau_base, tau_adapt_b, out_tau,
      out_h, nullptr, hB_bf, nullptr);                          // h3
  gemm128x256<2048, 1, false><<<512, 512, 0, stream>>>(
      hB_bf, Wcat, xtaub, icb, nullptr, tau_base, tau_adapt_b, out_h,
      out_tau, nullptr, hA_bf, nullptr);                        // h4
  gemm128x256<2048, 1, true><<<512, 512, 0, stream>>>(
      hA_bf, Wcat, xtaub, icb, nullptr, tau_base, tau_adapt_b, out_tau,
      out_h, out_tau, hB_bf, nullptr);                          // h5 + tau
}